// Round 1
// baseline (845.013 us; speedup 1.0000x reference)
//
#include <hip/hip_runtime.h>
#include <cstdint>

#define FDIM 128

// ---------------------------------------------------------------------------
// QKV GEMM: out[N,128] = act(x[N,128] @ W[128,128] + b), act=relu for Q,K.
// grid = (ceil(N/32), 3), block = 256. Each block: 32 rows x 128 cols.
// xs padded to 132 floats/row: LDS bank = (4*row + k) % 32 -> conflict-free
// across the wave's 8 distinct rows.
// ---------------------------------------------------------------------------
__global__ __launch_bounds__(256) void qkv_gemm_k(
    const float* __restrict__ x,
    const float* __restrict__ Wq, const float* __restrict__ bq,
    const float* __restrict__ Wk, const float* __restrict__ bk,
    const float* __restrict__ Wv, const float* __restrict__ bv,
    float* __restrict__ Q, float* __restrict__ K, float* __restrict__ V,
    int N)
{
    __shared__ float xs[32][132];
    const int mat = blockIdx.y;
    const float* __restrict__ W = (mat == 0) ? Wq : (mat == 1) ? Wk : Wv;
    const float* __restrict__ b = (mat == 0) ? bq : (mat == 1) ? bk : bv;
    float* __restrict__ out = (mat == 0) ? Q : (mat == 1) ? K : V;
    const int r0 = blockIdx.x * 32;
    const int tid = threadIdx.x;

    // stage 32x128 x-tile (1024 float4, 4 per thread)
    #pragma unroll
    for (int i = 0; i < 4; ++i) {
        int idx = tid + i * 256;
        int rr = idx >> 5;           // 32 float4 per row
        int cc = (idx & 31) << 2;
        float4 v = make_float4(0.f, 0.f, 0.f, 0.f);
        if (r0 + rr < N) v = *(const float4*)(x + (size_t)(r0 + rr) * FDIM + cc);
        *(float4*)(&xs[rr][cc]) = v;
    }
    __syncthreads();

    const int row = tid >> 3;        // 0..31
    const int cb  = (tid & 7) << 4;  // 0,16,...,112

    float acc[16];
    #pragma unroll
    for (int j = 0; j < 4; ++j) {
        float4 bb = *(const float4*)(b + cb + 4 * j);
        acc[4*j+0] = bb.x; acc[4*j+1] = bb.y; acc[4*j+2] = bb.z; acc[4*j+3] = bb.w;
    }

    #pragma unroll 4
    for (int k = 0; k < FDIM; ++k) {
        float xv = xs[row][k];
        const float4* wp = (const float4*)(W + (size_t)k * FDIM + cb);
        float4 w0 = wp[0], w1 = wp[1], w2 = wp[2], w3 = wp[3];
        acc[0]  += xv * w0.x; acc[1]  += xv * w0.y; acc[2]  += xv * w0.z; acc[3]  += xv * w0.w;
        acc[4]  += xv * w1.x; acc[5]  += xv * w1.y; acc[6]  += xv * w1.z; acc[7]  += xv * w1.w;
        acc[8]  += xv * w2.x; acc[9]  += xv * w2.y; acc[10] += xv * w2.z; acc[11] += xv * w2.w;
        acc[12] += xv * w3.x; acc[13] += xv * w3.y; acc[14] += xv * w3.z; acc[15] += xv * w3.w;
    }

    const int r = r0 + row;
    if (r < N) {
        #pragma unroll
        for (int j = 0; j < 4; ++j) {
            float4 o;
            o.x = acc[4*j+0]; o.y = acc[4*j+1]; o.z = acc[4*j+2]; o.w = acc[4*j+3];
            if (mat < 2) {  // relu for Q and K
                o.x = fmaxf(o.x, 0.f); o.y = fmaxf(o.y, 0.f);
                o.z = fmaxf(o.z, 0.f); o.w = fmaxf(o.w, 0.f);
            }
            *(float4*)(out + (size_t)r * FDIM + cb + 4 * j) = o;
        }
    }
}

// ---------------------------------------------------------------------------
// CSR build: histogram of in-degree (targets = edge_index[0]); self-loops are
// handled implicitly in aggregate_k and excluded from the CSR.
// ---------------------------------------------------------------------------
__global__ __launch_bounds__(256) void hist_k(const int* __restrict__ ei, int E,
                                              int* __restrict__ deg)
{
    int e = blockIdx.x * 256 + threadIdx.x;
    if (e < E) atomicAdd(&deg[ei[e]], 1);
}

// Block-local exclusive scan (256 elems), block sums to bsum.
__global__ __launch_bounds__(256) void scan_block_k(const int* __restrict__ deg,
                                                    int* __restrict__ offs,
                                                    int* __restrict__ bsum, int N)
{
    __shared__ int sh[256];
    int g = blockIdx.x * 256 + threadIdx.x;
    int v = (g < N) ? deg[g] : 0;
    sh[threadIdx.x] = v;
    __syncthreads();
    for (int s = 1; s < 256; s <<= 1) {
        int t = (threadIdx.x >= s) ? sh[threadIdx.x - s] : 0;
        __syncthreads();
        sh[threadIdx.x] += t;
        __syncthreads();
    }
    if (g < N) offs[g] = sh[threadIdx.x] - v;   // exclusive
    if (threadIdx.x == 255) bsum[blockIdx.x] = sh[255];
}

// Exclusive scan of <=256 block sums in one block.
__global__ __launch_bounds__(256) void scan_tops_k(int* __restrict__ bsum, int nb)
{
    __shared__ int sh[256];
    int v = (threadIdx.x < nb) ? bsum[threadIdx.x] : 0;
    sh[threadIdx.x] = v;
    __syncthreads();
    for (int s = 1; s < 256; s <<= 1) {
        int t = (threadIdx.x >= s) ? sh[threadIdx.x - s] : 0;
        __syncthreads();
        sh[threadIdx.x] += t;
        __syncthreads();
    }
    if (threadIdx.x < nb) bsum[threadIdx.x] = sh[threadIdx.x] - v;
}

__global__ __launch_bounds__(256) void scan_add_k(int* __restrict__ offs,
                                                  int* __restrict__ cursor,
                                                  const int* __restrict__ bsum, int N)
{
    int g = blockIdx.x * 256 + threadIdx.x;
    if (g < N) {
        int o = offs[g] + bsum[blockIdx.x];
        offs[g] = o;
        cursor[g] = o;
    }
}

// Fill csr: source node per slot (order within a node arbitrary; sums commute
// within tolerance).
__global__ __launch_bounds__(256) void scatter_k(const int* __restrict__ ei, int E,
                                                 int* __restrict__ cursor,
                                                 int* __restrict__ csr)
{
    int e = blockIdx.x * 256 + threadIdx.x;
    if (e < E) {
        int row = ei[e];         // target
        int col = ei[E + e];     // source
        int slot = atomicAdd(&cursor[row], 1);
        csr[slot] = col;
    }
}

// ---------------------------------------------------------------------------
// Aggregation: one wave (64 lanes) per target node. Lane l owns out dims
// 2l,2l+1 (head = l/8). Scores >= 0 (relu'd Q,K) and bounded (~13), so
// softmax without max subtraction is safe in fp32 -> single pass.
// Self-loop processed first (col=n), then the node's CSR edges.
// ---------------------------------------------------------------------------
__global__ __launch_bounds__(256) void aggregate_k(
    const float* __restrict__ Q, const float* __restrict__ K,
    const float* __restrict__ V,
    const int* __restrict__ offs, const int* __restrict__ deg,
    const int* __restrict__ csr,
    const float* __restrict__ bias, float* __restrict__ out, int N)
{
    const int lane = threadIdx.x & 63;
    const int n = blockIdx.x * 4 + (threadIdx.x >> 6);
    if (n >= N) return;

    const int d   = deg[n];
    const int off = offs[n];
    const float2 q = *(const float2*)(Q + (size_t)n * FDIM + 2 * lane);

    float acc0 = 0.f, acc1 = 0.f, lsum = 0.f;
    int col = n;  // self-loop first
    for (int i = 0; i <= d; ++i) {
        const float2 kk = *(const float2*)(K + (size_t)col * FDIM + 2 * lane);
        const float2 vv = *(const float2*)(V + (size_t)col * FDIM + 2 * lane);
        int ncol = (i < d) ? csr[off + i] : 0;   // prefetch next col index

        float p = q.x * kk.x + q.y * kk.y;
        p += __shfl_xor(p, 1);
        p += __shfl_xor(p, 2);
        p += __shfl_xor(p, 4);   // 8-lane head group fully reduced
        float s = __expf(p);
        lsum += s;
        acc0 += s * vv.x;
        acc1 += s * vv.y;
        col = ncol;
    }

    const float inv = 1.0f / lsum;   // lsum >= exp(self) > 0
    float2 o;
    o.x = acc0 * inv + bias[2 * lane];
    o.y = acc1 * inv + bias[2 * lane + 1];
    *(float2*)(out + (size_t)n * FDIM + 2 * lane) = o;
}

// ---------------------------------------------------------------------------
extern "C" void kernel_launch(void* const* d_in, const int* in_sizes, int n_in,
                              void* d_out, int out_size, void* d_ws, size_t ws_size,
                              hipStream_t stream)
{
    const float* x  = (const float*)d_in[0];
    const int*   ei = (const int*)d_in[1];
    const float* Wq = (const float*)d_in[2];
    const float* bq = (const float*)d_in[3];
    const float* Wk = (const float*)d_in[4];
    const float* bk = (const float*)d_in[5];
    const float* Wv = (const float*)d_in[6];
    const float* bv = (const float*)d_in[7];
    float* out = (float*)d_out;

    const int N = in_sizes[0] / FDIM;
    const int E = in_sizes[1] / 2;

    // workspace layout (~81 MB for N=50000, E=800000)
    float* Q = (float*)d_ws;
    float* K = Q + (size_t)N * FDIM;
    float* V = K + (size_t)N * FDIM;
    int* deg    = (int*)(V + (size_t)N * FDIM);
    int* offs   = deg + N;
    int* cursor = offs + N;
    int* bsum   = cursor + N;
    int* csr    = bsum + 1024;

    hipMemsetAsync(deg, 0, (size_t)N * sizeof(int), stream);

    dim3 gg((N + 31) / 32, 3);
    qkv_gemm_k<<<gg, 256, 0, stream>>>(x, Wq, bq, Wk, bk, Wv, bv, Q, K, V, N);

    hist_k<<<(E + 255) / 256, 256, 0, stream>>>(ei, E, deg);

    const int nb = (N + 255) / 256;   // 196 <= 256: single-block top scan ok
    scan_block_k<<<nb, 256, 0, stream>>>(deg, offs, bsum, N);
    scan_tops_k<<<1, 256, 0, stream>>>(bsum, nb);
    scan_add_k<<<nb, 256, 0, stream>>>(offs, cursor, bsum, N);

    scatter_k<<<(E + 255) / 256, 256, 0, stream>>>(ei, E, cursor, csr);

    aggregate_k<<<(N + 3) / 4, 256, 0, stream>>>(Q, K, V, offs, deg, csr,
                                                 bv /*unused*/, out, N);
    // NOTE: final bias is d_in[7] (bv is 'bias' of the output projection in
    // setup_inputs order: index 7). Passed above as `bv`.
}

// Round 2
// 416.196 us; speedup vs baseline: 2.0303x; 2.0303x over previous
//
#include <hip/hip_runtime.h>
#include <cstdint>

#define FDIM 128

// ---------------------------------------------------------------------------
// QKV GEMM: out[N,128] = act(x[N,128] @ W[128,128] + b), act=relu for Q,K.
// grid = (ceil(N/128), 3), block = 256.
// Hot loop is LDS-only: W fully staged (bank-swizzled), 128-row x tile with
// stride 129 (conflict-free b32 row reads). Thread = 4 rows x 16 cols ->
// 64 FMAs per 8 LDS instructions per k => VALU-bound.
// LDS = 131.6 KB -> 1 block/CU, 2 waves/SIMD; inner loop has 64-way ILP.
// ---------------------------------------------------------------------------
__global__ __launch_bounds__(256, 2) void qkv_gemm_k(
    const float* __restrict__ x,
    const float* __restrict__ Wq, const float* __restrict__ bq,
    const float* __restrict__ Wk, const float* __restrict__ bk,
    const float* __restrict__ Wv, const float* __restrict__ bv,
    float* __restrict__ Q, float* __restrict__ K, float* __restrict__ V,
    int N)
{
    __shared__ float xs[128 * 129];   // 66.0 KB
    __shared__ float ws[128 * 128];   // 64.0 KB

    const int mat = blockIdx.y;
    const float* __restrict__ W = (mat == 0) ? Wq : (mat == 1) ? Wk : Wv;
    const float* __restrict__ b = (mat == 0) ? bq : (mat == 1) ? bk : bv;
    float* __restrict__ out = (mat == 0) ? Q : (mat == 1) ? K : V;

    const int r0 = blockIdx.x * 128;
    const int tid = threadIdx.x;

    // ---- stage x tile: 128 rows x 128 cols at stride 129 ----
    #pragma unroll
    for (int j = 0; j < 16; ++j) {
        int f = j * 256 + tid;
        int row = f >> 5;              // 32 float4 per row
        int c = (f & 31) << 2;
        float4 v = make_float4(0.f, 0.f, 0.f, 0.f);
        if (r0 + row < N) v = *(const float4*)(x + (size_t)(r0 + row) * FDIM + c);
        float* p = xs + row * 129 + c;
        p[0] = v.x; p[1] = v.y; p[2] = v.z; p[3] = v.w;
    }

    // ---- stage W, bank-swizzled: logical col c = 16*cg + 4*jj + i is stored
    // at float4 slot k*32 + 8*jj + cg. Read side (fixed jj): 8 cg-spans land
    // on 8 distinct 4-bank groups -> conflict-free ds_read_b128. ----
    float4* ws4 = (float4*)ws;
    #pragma unroll
    for (int j = 0; j < 16; ++j) {
        int f = j * 256 + tid;
        int k = f >> 5;
        int c4 = (f & 31) << 2;
        int cg = c4 >> 4;
        int jj = (c4 >> 2) & 3;
        ws4[k * 32 + 8 * jj + cg] = *(const float4*)(W + (size_t)k * FDIM + c4);
    }
    __syncthreads();

    const int cg = tid & 7;            // col group: 16 cols
    const int rg = tid >> 3;           // 0..31; rows rg, rg+32, rg+64, rg+96
    const int cb = cg << 4;

    float acc[4][16];
    #pragma unroll
    for (int jj = 0; jj < 4; ++jj) {
        float4 bb = *(const float4*)(b + cb + 4 * jj);
        #pragma unroll
        for (int m = 0; m < 4; ++m) {
            acc[m][4*jj+0] = bb.x; acc[m][4*jj+1] = bb.y;
            acc[m][4*jj+2] = bb.z; acc[m][4*jj+3] = bb.w;
        }
    }

    #pragma unroll 4
    for (int k = 0; k < FDIM; ++k) {
        const float4 w0 = ws4[k * 32 +      cg];
        const float4 w1 = ws4[k * 32 +  8 + cg];
        const float4 w2 = ws4[k * 32 + 16 + cg];
        const float4 w3 = ws4[k * 32 + 24 + cg];
        float xv[4];
        #pragma unroll
        for (int m = 0; m < 4; ++m) xv[m] = xs[(rg + 32 * m) * 129 + k];
        #pragma unroll
        for (int m = 0; m < 4; ++m) {
            float xm = xv[m];
            acc[m][0]  += xm * w0.x; acc[m][1]  += xm * w0.y;
            acc[m][2]  += xm * w0.z; acc[m][3]  += xm * w0.w;
            acc[m][4]  += xm * w1.x; acc[m][5]  += xm * w1.y;
            acc[m][6]  += xm * w1.z; acc[m][7]  += xm * w1.w;
            acc[m][8]  += xm * w2.x; acc[m][9]  += xm * w2.y;
            acc[m][10] += xm * w2.z; acc[m][11] += xm * w2.w;
            acc[m][12] += xm * w3.x; acc[m][13] += xm * w3.y;
            acc[m][14] += xm * w3.z; acc[m][15] += xm * w3.w;
        }
    }

    #pragma unroll
    for (int m = 0; m < 4; ++m) {
        int r = r0 + rg + 32 * m;
        if (r < N) {
            #pragma unroll
            for (int jj = 0; jj < 4; ++jj) {
                float4 o;
                o.x = acc[m][4*jj+0]; o.y = acc[m][4*jj+1];
                o.z = acc[m][4*jj+2]; o.w = acc[m][4*jj+3];
                if (mat < 2) {  // relu for Q and K
                    o.x = fmaxf(o.x, 0.f); o.y = fmaxf(o.y, 0.f);
                    o.z = fmaxf(o.z, 0.f); o.w = fmaxf(o.w, 0.f);
                }
                *(float4*)(out + (size_t)r * FDIM + cb + 4 * jj) = o;
            }
        }
    }
}

// ---------------------------------------------------------------------------
// CSR build: histogram of in-degree (targets = edge_index[0]); self-loops are
// handled implicitly in aggregate_k and excluded from the CSR.
// ---------------------------------------------------------------------------
__global__ __launch_bounds__(256) void hist_k(const int* __restrict__ ei, int E,
                                              int* __restrict__ deg)
{
    int e = blockIdx.x * 256 + threadIdx.x;
    if (e < E) atomicAdd(&deg[ei[e]], 1);
}

__global__ __launch_bounds__(256) void scan_block_k(const int* __restrict__ deg,
                                                    int* __restrict__ offs,
                                                    int* __restrict__ bsum, int N)
{
    __shared__ int sh[256];
    int g = blockIdx.x * 256 + threadIdx.x;
    int v = (g < N) ? deg[g] : 0;
    sh[threadIdx.x] = v;
    __syncthreads();
    for (int s = 1; s < 256; s <<= 1) {
        int t = (threadIdx.x >= s) ? sh[threadIdx.x - s] : 0;
        __syncthreads();
        sh[threadIdx.x] += t;
        __syncthreads();
    }
    if (g < N) offs[g] = sh[threadIdx.x] - v;   // exclusive
    if (threadIdx.x == 255) bsum[blockIdx.x] = sh[255];
}

__global__ __launch_bounds__(256) void scan_tops_k(int* __restrict__ bsum, int nb)
{
    __shared__ int sh[256];
    int v = (threadIdx.x < nb) ? bsum[threadIdx.x] : 0;
    sh[threadIdx.x] = v;
    __syncthreads();
    for (int s = 1; s < 256; s <<= 1) {
        int t = (threadIdx.x >= s) ? sh[threadIdx.x - s] : 0;
        __syncthreads();
        sh[threadIdx.x] += t;
        __syncthreads();
    }
    if (threadIdx.x < nb) bsum[threadIdx.x] = sh[threadIdx.x] - v;
}

__global__ __launch_bounds__(256) void scan_add_k(int* __restrict__ offs,
                                                  int* __restrict__ cursor,
                                                  const int* __restrict__ bsum, int N)
{
    int g = blockIdx.x * 256 + threadIdx.x;
    if (g < N) {
        int o = offs[g] + bsum[blockIdx.x];
        offs[g] = o;
        cursor[g] = o;
    }
}

__global__ __launch_bounds__(256) void scatter_k(const int* __restrict__ ei, int E,
                                                 int* __restrict__ cursor,
                                                 int* __restrict__ csr)
{
    int e = blockIdx.x * 256 + threadIdx.x;
    if (e < E) {
        int row = ei[e];         // target
        int col = ei[E + e];     // source
        int slot = atomicAdd(&cursor[row], 1);
        csr[slot] = col;
    }
}

// ---------------------------------------------------------------------------
// Aggregation: one wave (64 lanes) per target node. Lane l owns out dims
// 2l,2l+1 (head = l/8). Scores >= 0 (relu'd Q,K) and bounded (~13), so
// softmax without max subtraction is safe in fp32 -> single pass.
// Final bias is already folded into V (sum of alpha over a segment == 1).
// ---------------------------------------------------------------------------
__global__ __launch_bounds__(256) void aggregate_k(
    const float* __restrict__ Q, const float* __restrict__ K,
    const float* __restrict__ V,
    const int* __restrict__ offs, const int* __restrict__ deg,
    const int* __restrict__ csr,
    float* __restrict__ out, int N)
{
    const int lane = threadIdx.x & 63;
    const int n = blockIdx.x * 4 + (threadIdx.x >> 6);
    if (n >= N) return;

    const int d   = deg[n];
    const int off = offs[n];
    const float2 q = *(const float2*)(Q + (size_t)n * FDIM + 2 * lane);

    float acc0 = 0.f, acc1 = 0.f, lsum = 0.f;
    int col = n;  // self-loop first
    for (int i = 0; i <= d; ++i) {
        const float2 kk = *(const float2*)(K + (size_t)col * FDIM + 2 * lane);
        const float2 vv = *(const float2*)(V + (size_t)col * FDIM + 2 * lane);
        int ncol = (i < d) ? csr[off + i] : 0;   // prefetch next col index

        float p = q.x * kk.x + q.y * kk.y;
        p += __shfl_xor(p, 1);
        p += __shfl_xor(p, 2);
        p += __shfl_xor(p, 4);   // 8-lane head group fully reduced
        float s = __expf(p);
        lsum += s;
        acc0 += s * vv.x;
        acc1 += s * vv.y;
        col = ncol;
    }

    const float inv = 1.0f / lsum;   // lsum >= exp(self) > 0
    float2 o;
    o.x = acc0 * inv;
    o.y = acc1 * inv;
    *(float2*)(out + (size_t)n * FDIM + 2 * lane) = o;
}

// ---------------------------------------------------------------------------
extern "C" void kernel_launch(void* const* d_in, const int* in_sizes, int n_in,
                              void* d_out, int out_size, void* d_ws, size_t ws_size,
                              hipStream_t stream)
{
    const float* x  = (const float*)d_in[0];
    const int*   ei = (const int*)d_in[1];
    const float* Wq = (const float*)d_in[2];
    const float* bq = (const float*)d_in[3];
    const float* Wk = (const float*)d_in[4];
    const float* bk = (const float*)d_in[5];
    const float* Wv = (const float*)d_in[6];
    const float* bias = (const float*)d_in[7];   // final bias, folded into V
    float* out = (float*)d_out;

    const int N = in_sizes[0] / FDIM;
    const int E = in_sizes[1] / 2;

    // workspace layout (~81 MB for N=50000, E=800000)
    float* Q = (float*)d_ws;
    float* K = Q + (size_t)N * FDIM;
    float* V = K + (size_t)N * FDIM;
    int* deg    = (int*)(V + (size_t)N * FDIM);
    int* offs   = deg + N;
    int* cursor = offs + N;
    int* bsum   = cursor + N;
    int* csr    = bsum + 1024;

    hipMemsetAsync(deg, 0, (size_t)N * sizeof(int), stream);

    dim3 gg((N + 127) / 128, 3);
    qkv_gemm_k<<<gg, 256, 0, stream>>>(x, Wq, bq, Wk, bk, Wv, bias, Q, K, V, N);

    hist_k<<<(E + 255) / 256, 256, 0, stream>>>(ei, E, deg);

    const int nb = (N + 255) / 256;   // 196 <= 256: single-block top scan ok
    scan_block_k<<<nb, 256, 0, stream>>>(deg, offs, bsum, N);
    scan_tops_k<<<1, 256, 0, stream>>>(bsum, nb);
    scan_add_k<<<nb, 256, 0, stream>>>(offs, cursor, bsum, N);

    scatter_k<<<(E + 255) / 256, 256, 0, stream>>>(ei, E, cursor, csr);

    aggregate_k<<<(N + 3) / 4, 256, 0, stream>>>(Q, K, V, offs, deg, csr, out, N);
}

// Round 3
// 352.147 us; speedup vs baseline: 2.3996x; 1.1819x over previous
//
#include <hip/hip_runtime.h>
#include <cstdint>

#define FDIM 128
#define XSTR 136   // padded row stride in bf16 elems (+8 elems = 16 B -> rotates 4-bank group per row)
#define NROWTILE 128

typedef __attribute__((ext_vector_type(8))) short short8;
typedef __attribute__((ext_vector_type(16))) float float16;

__device__ __forceinline__ unsigned short f2bf(float f) {   // RNE
    unsigned int u = __float_as_uint(f);
    return (unsigned short)((u + 0x7fffu + ((u >> 16) & 1)) >> 16);
}
__device__ __forceinline__ float bf_lo(unsigned int p) { return __uint_as_float(p << 16); }
__device__ __forceinline__ float bf_hi(unsigned int p) { return __uint_as_float(p & 0xffff0000u); }

__device__ __forceinline__ void gload_lds16(const void* g, void* s) {
    __builtin_amdgcn_global_load_lds(
        (const __attribute__((address_space(1))) void*)g,
        (__attribute__((address_space(3))) void*)s, 16, 0, 0);
}

// ---------------------------------------------------------------------------
// Convert x (fp32) -> padded bf16 hi/lo images [Npad x XSTR]. Rows >= N zero.
// ---------------------------------------------------------------------------
__global__ __launch_bounds__(256) void convert_x_k(
    const float* __restrict__ x, unsigned short* __restrict__ XH,
    unsigned short* __restrict__ XL, int N, int Npad)
{
    int idx = blockIdx.x * 256 + threadIdx.x;       // one float4 of x
    int row = idx >> 5;
    int c = (idx & 31) << 2;
    if (row >= Npad) return;
    float4 v = make_float4(0.f, 0.f, 0.f, 0.f);
    if (row < N) v = *(const float4*)(x + (size_t)row * FDIM + c);
    unsigned short h[4], l[4];
    float vv[4] = {v.x, v.y, v.z, v.w};
    #pragma unroll
    for (int i = 0; i < 4; ++i) {
        h[i] = f2bf(vv[i]);
        float hf = __uint_as_float(((unsigned int)h[i]) << 16);
        l[i] = f2bf(vv[i] - hf);
    }
    ushort4 hh = {h[0], h[1], h[2], h[3]};
    ushort4 ll = {l[0], l[1], l[2], l[3]};
    *(ushort4*)(XH + (size_t)row * XSTR + c) = hh;
    *(ushort4*)(XL + (size_t)row * XSTR + c) = ll;
}

// ---------------------------------------------------------------------------
// Convert + transpose W (fp32 [K=128][N=128]) -> Wt hi/lo images [n*XSTR + k].
// grid.x = 3 (mat). Tiny kernel.
// ---------------------------------------------------------------------------
__global__ __launch_bounds__(256) void convert_w_k(
    const float* __restrict__ Wq, const float* __restrict__ Wk,
    const float* __restrict__ Wv,
    unsigned short* __restrict__ WTH, unsigned short* __restrict__ WTL)
{
    const int mat = blockIdx.x;
    const float* __restrict__ W = (mat == 0) ? Wq : (mat == 1) ? Wk : Wv;
    unsigned short* th = WTH + (size_t)mat * FDIM * XSTR;
    unsigned short* tl = WTL + (size_t)mat * FDIM * XSTR;
    for (int t = 0; t < 64; ++t) {
        int idx = t * 256 + threadIdx.x;     // 16384 elems
        int k = idx >> 7;
        int n = idx & 127;
        float w = W[k * FDIM + n];
        unsigned short h = f2bf(w);
        float hf = __uint_as_float(((unsigned int)h) << 16);
        th[n * XSTR + k] = h;
        tl[n * XSTR + k] = f2bf(w - hf);
    }
}

// ---------------------------------------------------------------------------
// MFMA GEMM: per block 128 rows x 128 cols, loops all 3 mats (x staged once).
// C = xh*Wh + xl*Wh + xh*Wl  (bf16 compensated, fp32 accumulate).
// Staging via global_load_lds width-16. Outputs Q/K/V in bf16 (relu for Q,K;
// final bias folded into V since sum(alpha)=1).
// LDS = 2*(128*136*2)*2 = 139 KB -> 1 block/CU.
// ---------------------------------------------------------------------------
__global__ __launch_bounds__(256) void gemm_mfma_k(
    const unsigned short* __restrict__ XH, const unsigned short* __restrict__ XL,
    const unsigned short* __restrict__ WTH, const unsigned short* __restrict__ WTL,
    const float* __restrict__ bq, const float* __restrict__ bk,
    const float* __restrict__ bias,
    unsigned short* __restrict__ Qb, unsigned short* __restrict__ Kb,
    unsigned short* __restrict__ Vb, int N)
{
    __shared__ unsigned short xs_h[NROWTILE * XSTR];
    __shared__ unsigned short xs_l[NROWTILE * XSTR];
    __shared__ unsigned short ws_h[FDIM * XSTR];
    __shared__ unsigned short ws_l[FDIM * XSTR];

    const int tid  = threadIdx.x;
    const int wave = tid >> 6;
    const int lane = tid & 63;
    const int r0   = blockIdx.x * NROWTILE;

    const int IMG_CHUNKS = (NROWTILE * XSTR * 2) / 1024;   // 34 x 1KB chunks

    // stage x hi/lo (each chunk: 64 lanes x 16 B)
    for (int c = wave; c < IMG_CHUNKS; c += 4) {
        const char* gh = (const char*)(XH + (size_t)r0 * XSTR) + c * 1024 + lane * 16;
        const char* gl = (const char*)(XL + (size_t)r0 * XSTR) + c * 1024 + lane * 16;
        gload_lds16(gh, (char*)xs_h + c * 1024);
        gload_lds16(gl, (char*)xs_l + c * 1024);
    }
    // stage W mat 0
    for (int c = wave; c < IMG_CHUNKS; c += 4) {
        gload_lds16((const char*)WTH + c * 1024 + lane * 16, (char*)ws_h + c * 1024);
        gload_lds16((const char*)WTL + c * 1024 + lane * 16, (char*)ws_l + c * 1024);
    }
    __syncthreads();

    const int mrow = lane & 31;    // row within 32-tile (A) / col within 32 (B,C)
    const int half = lane >> 5;    // 0/1
    const int arow = wave * 32 + mrow;

    for (int mat = 0; mat < 3; ++mat) {
        float16 acc[4];
        #pragma unroll
        for (int nt = 0; nt < 4; ++nt)
            #pragma unroll
            for (int r = 0; r < 16; ++r) acc[nt][r] = 0.f;

        #pragma unroll
        for (int ks = 0; ks < 8; ++ks) {
            const int ko = ks * 16 + half * 8;
            short8 ah = *(const short8*)(xs_h + arow * XSTR + ko);
            short8 al = *(const short8*)(xs_l + arow * XSTR + ko);
            #pragma unroll
            for (int nt = 0; nt < 4; ++nt) {
                short8 bh = *(const short8*)(ws_h + (nt * 32 + mrow) * XSTR + ko);
                short8 bl = *(const short8*)(ws_l + (nt * 32 + mrow) * XSTR + ko);
                acc[nt] = __builtin_amdgcn_mfma_f32_32x32x16_bf16(ah, bh, acc[nt], 0, 0, 0);
                acc[nt] = __builtin_amdgcn_mfma_f32_32x32x16_bf16(al, bh, acc[nt], 0, 0, 0);
                acc[nt] = __builtin_amdgcn_mfma_f32_32x32x16_bf16(ah, bl, acc[nt], 0, 0, 0);
            }
        }

        // prefetch next mat's W while epilogue runs
        __syncthreads();
        if (mat < 2) {
            const char* nh = (const char*)(WTH + (size_t)(mat + 1) * FDIM * XSTR);
            const char* nl = (const char*)(WTL + (size_t)(mat + 1) * FDIM * XSTR);
            for (int c = wave; c < IMG_CHUNKS; c += 4) {
                gload_lds16(nh + c * 1024 + lane * 16, (char*)ws_h + c * 1024);
                gload_lds16(nl + c * 1024 + lane * 16, (char*)ws_l + c * 1024);
            }
        }

        // epilogue: C/D layout col=lane&31, row=(reg&3)+8*(reg>>2)+4*(lane>>5)
        const float* bvec = (mat == 0) ? bq : (mat == 1) ? bk : bias;
        unsigned short* outp = (mat == 0) ? Qb : (mat == 1) ? Kb : Vb;
        #pragma unroll
        for (int nt = 0; nt < 4; ++nt) {
            const int col = nt * 32 + mrow;
            const float bb = bvec[col];
            #pragma unroll
            for (int reg = 0; reg < 16; ++reg) {
                int rl = (reg & 3) + 8 * (reg >> 2) + 4 * half;
                int row = r0 + wave * 32 + rl;
                if (row < N) {
                    float v = acc[nt][reg] + bb;
                    if (mat < 2) v = fmaxf(v, 0.f);
                    outp[(size_t)row * FDIM + col] = f2bf(v);
                }
            }
        }
        __syncthreads();
    }
}

// ---------------------------------------------------------------------------
// CSR build (unchanged)
// ---------------------------------------------------------------------------
__global__ __launch_bounds__(256) void hist_k(const int* __restrict__ ei, int E,
                                              int* __restrict__ deg)
{
    int e = blockIdx.x * 256 + threadIdx.x;
    if (e < E) atomicAdd(&deg[ei[e]], 1);
}

__global__ __launch_bounds__(256) void scan_block_k(const int* __restrict__ deg,
                                                    int* __restrict__ offs,
                                                    int* __restrict__ bsum, int N)
{
    __shared__ int sh[256];
    int g = blockIdx.x * 256 + threadIdx.x;
    int v = (g < N) ? deg[g] : 0;
    sh[threadIdx.x] = v;
    __syncthreads();
    for (int s = 1; s < 256; s <<= 1) {
        int t = (threadIdx.x >= s) ? sh[threadIdx.x - s] : 0;
        __syncthreads();
        sh[threadIdx.x] += t;
        __syncthreads();
    }
    if (g < N) offs[g] = sh[threadIdx.x] - v;
    if (threadIdx.x == 255) bsum[blockIdx.x] = sh[255];
}

__global__ __launch_bounds__(256) void scan_tops_k(int* __restrict__ bsum, int nb)
{
    __shared__ int sh[256];
    int v = (threadIdx.x < nb) ? bsum[threadIdx.x] : 0;
    sh[threadIdx.x] = v;
    __syncthreads();
    for (int s = 1; s < 256; s <<= 1) {
        int t = (threadIdx.x >= s) ? sh[threadIdx.x - s] : 0;
        __syncthreads();
        sh[threadIdx.x] += t;
        __syncthreads();
    }
    if (threadIdx.x < nb) bsum[threadIdx.x] = sh[threadIdx.x] - v;
}

__global__ __launch_bounds__(256) void scan_add_k(int* __restrict__ offs,
                                                  int* __restrict__ cursor,
                                                  const int* __restrict__ bsum, int N)
{
    int g = blockIdx.x * 256 + threadIdx.x;
    if (g < N) {
        int o = offs[g] + bsum[blockIdx.x];
        offs[g] = o;
        cursor[g] = o;
    }
}

__global__ __launch_bounds__(256) void scatter_k(const int* __restrict__ ei, int E,
                                                 int* __restrict__ cursor,
                                                 int* __restrict__ csr)
{
    int e = blockIdx.x * 256 + threadIdx.x;
    if (e < E) {
        int row = ei[e];
        int col = ei[E + e];
        int slot = atomicAdd(&cursor[row], 1);
        csr[slot] = col;
    }
}

// ---------------------------------------------------------------------------
// Aggregation over bf16 Q/K/V: one wave per node; lane l owns dims 2l,2l+1.
// Scores >= 0 and bounded -> single-pass softmax (no max subtraction).
// ---------------------------------------------------------------------------
__global__ __launch_bounds__(256) void aggregate_k(
    const unsigned short* __restrict__ Qb, const unsigned short* __restrict__ Kb,
    const unsigned short* __restrict__ Vb,
    const int* __restrict__ offs, const int* __restrict__ deg,
    const int* __restrict__ csr,
    float* __restrict__ out, int N)
{
    const int lane = threadIdx.x & 63;
    const int n = blockIdx.x * 4 + (threadIdx.x >> 6);
    if (n >= N) return;

    const int d   = deg[n];
    const int off = offs[n];
    const unsigned int qu = *(const unsigned int*)(Qb + (size_t)n * FDIM + 2 * lane);
    const float qx = bf_lo(qu), qy = bf_hi(qu);

    float acc0 = 0.f, acc1 = 0.f, lsum = 0.f;
    int col = n;  // self-loop first
    for (int i = 0; i <= d; ++i) {
        const unsigned int ku = *(const unsigned int*)(Kb + (size_t)col * FDIM + 2 * lane);
        const unsigned int vu = *(const unsigned int*)(Vb + (size_t)col * FDIM + 2 * lane);
        int ncol = (i < d) ? csr[off + i] : 0;   // prefetch next col index

        float p = qx * bf_lo(ku) + qy * bf_hi(ku);
        p += __shfl_xor(p, 1);
        p += __shfl_xor(p, 2);
        p += __shfl_xor(p, 4);   // 8-lane head group fully reduced
        float s = __expf(p);
        lsum += s;
        acc0 += s * bf_lo(vu);
        acc1 += s * bf_hi(vu);
        col = ncol;
    }

    const float inv = 1.0f / lsum;
    float2 o;
    o.x = acc0 * inv;
    o.y = acc1 * inv;
    *(float2*)(out + (size_t)n * FDIM + 2 * lane) = o;
}

// ---------------------------------------------------------------------------
extern "C" void kernel_launch(void* const* d_in, const int* in_sizes, int n_in,
                              void* d_out, int out_size, void* d_ws, size_t ws_size,
                              hipStream_t stream)
{
    const float* x    = (const float*)d_in[0];
    const int*   ei   = (const int*)d_in[1];
    const float* Wq   = (const float*)d_in[2];
    const float* bq   = (const float*)d_in[3];
    const float* Wk   = (const float*)d_in[4];
    const float* bk   = (const float*)d_in[5];
    const float* Wv   = (const float*)d_in[6];
    const float* bias = (const float*)d_in[7];   // final bias, folded into V
    float* out = (float*)d_out;

    const int N = in_sizes[0] / FDIM;
    const int E = in_sizes[1] / 2;
    const int nblk = (N + NROWTILE - 1) / NROWTILE;
    const int Npad = nblk * NROWTILE;

    // workspace layout (~70 MB)
    unsigned short* XH  = (unsigned short*)d_ws;
    unsigned short* XL  = XH + (size_t)Npad * XSTR;
    unsigned short* WTH = XL + (size_t)Npad * XSTR;
    unsigned short* WTL = WTH + (size_t)3 * FDIM * XSTR;
    unsigned short* Qb  = WTL + (size_t)3 * FDIM * XSTR;
    unsigned short* Kb  = Qb + (size_t)N * FDIM;
    unsigned short* Vb  = Kb + (size_t)N * FDIM;
    int* deg    = (int*)(Vb + (size_t)N * FDIM);
    int* offs   = deg + N;
    int* cursor = offs + N;
    int* bsum   = cursor + N;
    int* csr    = bsum + 1024;

    hipMemsetAsync(deg, 0, (size_t)N * sizeof(int), stream);

    convert_x_k<<<(Npad * 32 + 255) / 256, 256, 0, stream>>>(x, XH, XL, N, Npad);
    convert_w_k<<<3, 256, 0, stream>>>(Wq, Wk, Wv, WTH, WTL);

    gemm_mfma_k<<<nblk, 256, 0, stream>>>(XH, XL, WTH, WTL, bq, bk, bias,
                                          Qb, Kb, Vb, N);

    hist_k<<<(E + 255) / 256, 256, 0, stream>>>(ei, E, deg);
    const int nb = (N + 255) / 256;
    scan_block_k<<<nb, 256, 0, stream>>>(deg, offs, bsum, N);
    scan_tops_k<<<1, 256, 0, stream>>>(bsum, nb);
    scan_add_k<<<nb, 256, 0, stream>>>(offs, cursor, bsum, N);
    scatter_k<<<(E + 255) / 256, 256, 0, stream>>>(ei, E, cursor, csr);

    aggregate_k<<<(N + 3) / 4, 256, 0, stream>>>(Qb, Kb, Vb, offs, deg, csr, out, N);
}

// Round 5
// 290.956 us; speedup vs baseline: 2.9043x; 1.2103x over previous
//
#include <hip/hip_runtime.h>
#include <hip/hip_fp16.h>
#include <cstdint>

#define FDIM 128
#define XSTR 136   // padded row stride in f16 elems (+8 elems = 16 B)
#define NROWTILE 128
#define WCHUNKS ((FDIM * XSTR * 2) / 1024)       // 34 x 1KB chunks per W image
#define XCHUNKS ((NROWTILE * XSTR * 2) / 1024)   // 34 x 1KB chunks per x tile

typedef __attribute__((ext_vector_type(8))) _Float16 half8;
typedef __attribute__((ext_vector_type(16))) float float16;

__device__ __forceinline__ void gload_lds16(const void* g, void* s) {
    __builtin_amdgcn_global_load_lds(
        (const __attribute__((address_space(1))) void*)g,
        (__attribute__((address_space(3))) void*)s, 16, 0, 0);
}

// ---------------------------------------------------------------------------
// Convert x (fp32) -> padded f16 image [Npad x XSTR]. Rows >= N zero.
// ---------------------------------------------------------------------------
__global__ __launch_bounds__(256) void convert_x_k(
    const float* __restrict__ x, __half* __restrict__ XH, int N, int Npad)
{
    int idx = blockIdx.x * 256 + threadIdx.x;       // one float4 of x
    int row = idx >> 5;
    int c = (idx & 31) << 2;
    if (row >= Npad) return;
    float4 v = make_float4(0.f, 0.f, 0.f, 0.f);
    if (row < N) v = *(const float4*)(x + (size_t)row * FDIM + c);
    __half h[4] = {__float2half_rn(v.x), __float2half_rn(v.y),
                   __float2half_rn(v.z), __float2half_rn(v.w)};
    *(ushort4*)(XH + (size_t)row * XSTR + c) = *(ushort4*)h;
}

// ---------------------------------------------------------------------------
// Convert + transpose W (fp32 [K=128][N=128]) -> Wt f16 image [n*XSTR + k].
// grid.x = 3 (mat).
// ---------------------------------------------------------------------------
__global__ __launch_bounds__(256) void convert_w_k(
    const float* __restrict__ Wq, const float* __restrict__ Wk,
    const float* __restrict__ Wv, __half* __restrict__ WTH)
{
    const int mat = blockIdx.x;
    const float* __restrict__ W = (mat == 0) ? Wq : (mat == 1) ? Wk : Wv;
    __half* th = WTH + (size_t)mat * FDIM * XSTR;
    for (int t = 0; t < 64; ++t) {
        int idx = t * 256 + threadIdx.x;     // 16384 elems
        int k = idx >> 7;
        int n = idx & 127;
        th[n * XSTR + k] = __float2half_rn(W[k * FDIM + n]);
    }
}

// ---------------------------------------------------------------------------
// MFMA GEMM (f16): per block 128 rows x 128 cols, loops all 3 mats.
// Outputs: Q -> f16 Qb[N][128]; K,V -> interleaved KV uint2[N][64]
// (dim pair 2j,2j+1: .x = K halves, .y = V halves) for single-load gathers.
// relu on Q,K; final bias folded into V (sum alpha = 1).
// LDS = 2 * 128*136*2 = 69.6 KB -> 2 blocks/CU.
// ---------------------------------------------------------------------------
__global__ __launch_bounds__(256) void gemm_mfma_k(
    const __half* __restrict__ XH, const __half* __restrict__ WTH,
    const float* __restrict__ bq, const float* __restrict__ bk,
    const float* __restrict__ bias,
    __half* __restrict__ Qb, uint2* __restrict__ KV, int N)
{
    __shared__ __half xs[NROWTILE * XSTR];
    __shared__ __half ws[FDIM * XSTR];

    const int tid  = threadIdx.x;
    const int wave = tid >> 6;
    const int lane = tid & 63;
    const int r0   = blockIdx.x * NROWTILE;

    for (int c = wave; c < XCHUNKS; c += 4) {
        gload_lds16((const char*)(XH + (size_t)r0 * XSTR) + c * 1024 + lane * 16,
                    (char*)xs + c * 1024);
        gload_lds16((const char*)WTH + c * 1024 + lane * 16,
                    (char*)ws + c * 1024);
    }
    __syncthreads();

    const int mrow = lane & 31;    // A row within 32-tile / B,C col within 32
    const int half = lane >> 5;    // 0/1
    const int arow = wave * 32 + mrow;

    for (int mat = 0; mat < 3; ++mat) {
        float16 acc[4];
        #pragma unroll
        for (int nt = 0; nt < 4; ++nt)
            #pragma unroll
            for (int r = 0; r < 16; ++r) acc[nt][r] = 0.f;

        #pragma unroll
        for (int ks = 0; ks < 8; ++ks) {
            const int ko = ks * 16 + half * 8;
            half8 ah = *(const half8*)(xs + arow * XSTR + ko);
            #pragma unroll
            for (int nt = 0; nt < 4; ++nt) {
                half8 bh = *(const half8*)(ws + (nt * 32 + mrow) * XSTR + ko);
                acc[nt] = __builtin_amdgcn_mfma_f32_32x32x16_f16(ah, bh, acc[nt], 0, 0, 0);
            }
        }

        __syncthreads();
        if (mat < 2) {   // prefetch next mat's FULL W image (34 chunks)
            const char* nh = (const char*)(WTH + (size_t)(mat + 1) * FDIM * XSTR);
            for (int c = wave; c < WCHUNKS; c += 4)
                gload_lds16(nh + c * 1024 + lane * 16, (char*)ws + c * 1024);
        }

        // epilogue: C/D layout col=lane&31, row=(reg&3)+8*(reg>>2)+4*(lane>>5)
        const float* bvec = (mat == 0) ? bq : (mat == 1) ? bk : bias;
        __half* kvh = (__half*)KV;
        #pragma unroll
        for (int nt = 0; nt < 4; ++nt) {
            const int col = nt * 32 + mrow;
            const float bb = bvec[col];
            #pragma unroll
            for (int reg = 0; reg < 16; ++reg) {
                int rl = (reg & 3) + 8 * (reg >> 2) + 4 * half;
                int row = r0 + wave * 32 + rl;
                if (row < N) {
                    float v = acc[nt][reg] + bb;
                    if (mat < 2) v = fmaxf(v, 0.f);
                    __half hv = __float2half_rn(v);
                    if (mat == 0) {
                        Qb[(size_t)row * FDIM + col] = hv;
                    } else {
                        // K at slot 0/1, V at slot 2/3 of the dim-pair group
                        kvh[(size_t)row * 256 + (col >> 1) * 4 + (col & 1) +
                            ((mat == 2) ? 2 : 0)] = hv;
                    }
                }
            }
        }
        __syncthreads();
    }
}

// ---------------------------------------------------------------------------
// CSR build
// ---------------------------------------------------------------------------
__global__ __launch_bounds__(256) void hist_k(const int* __restrict__ ei, int E,
                                              int* __restrict__ deg)
{
    int e = blockIdx.x * 256 + threadIdx.x;
    if (e < E) atomicAdd(&deg[ei[e]], 1);
}

__global__ __launch_bounds__(256) void scan_block_k(const int* __restrict__ deg,
                                                    int* __restrict__ offs,
                                                    int* __restrict__ bsum, int N)
{
    __shared__ int sh[256];
    int g = blockIdx.x * 256 + threadIdx.x;
    int v = (g < N) ? deg[g] : 0;
    sh[threadIdx.x] = v;
    __syncthreads();
    for (int s = 1; s < 256; s <<= 1) {
        int t = (threadIdx.x >= s) ? sh[threadIdx.x - s] : 0;
        __syncthreads();
        sh[threadIdx.x] += t;
        __syncthreads();
    }
    if (g < N) offs[g] = sh[threadIdx.x] - v;
    if (threadIdx.x == 255) bsum[blockIdx.x] = sh[255];
}

__global__ __launch_bounds__(256) void scan_tops_k(int* __restrict__ bsum, int nb)
{
    __shared__ int sh[256];
    int v = (threadIdx.x < nb) ? bsum[threadIdx.x] : 0;
    sh[threadIdx.x] = v;
    __syncthreads();
    for (int s = 1; s < 256; s <<= 1) {
        int t = (threadIdx.x >= s) ? sh[threadIdx.x - s] : 0;
        __syncthreads();
        sh[threadIdx.x] += t;
        __syncthreads();
    }
    if (threadIdx.x < nb) bsum[threadIdx.x] = sh[threadIdx.x] - v;
}

__global__ __launch_bounds__(256) void scan_add_k(int* __restrict__ offs,
                                                  int* __restrict__ cursor,
                                                  const int* __restrict__ bsum, int N)
{
    int g = blockIdx.x * 256 + threadIdx.x;
    if (g < N) {
        int o = offs[g] + bsum[blockIdx.x];
        offs[g] = o;
        cursor[g] = o;
    }
}

__global__ __launch_bounds__(256) void scatter_k(const int* __restrict__ ei, int E,
                                                 int* __restrict__ cursor,
                                                 int* __restrict__ csr)
{
    int e = blockIdx.x * 256 + threadIdx.x;
    if (e < E) {
        int row = ei[e];
        int col = ei[E + e];
        int slot = atomicAdd(&cursor[row], 1);
        csr[slot] = col;
    }
}

// ---------------------------------------------------------------------------
// Aggregation: one wave per node; lane l owns dims 2l,2l+1 (head = l/8).
// Single uint2 gather per edge (K+V interleaved), unroll-2 index pipeline,
// scalarized loop control. Scores >= 0 and bounded -> no max subtraction.
// ---------------------------------------------------------------------------
__global__ __launch_bounds__(256) void aggregate_k(
    const __half* __restrict__ Qb, const uint2* __restrict__ KV,
    const int* __restrict__ offs, const int* __restrict__ deg,
    const int* __restrict__ csr,
    float* __restrict__ out, int N)
{
    const int lane = threadIdx.x & 63;
    int n = blockIdx.x * 4 + (threadIdx.x >> 6);
    if (n >= N) return;
    n = __builtin_amdgcn_readfirstlane(n);

    const int d   = __builtin_amdgcn_readfirstlane(deg[n]);
    const int off = __builtin_amdgcn_readfirstlane(offs[n]);

    __half2 qh = *(const __half2*)(Qb + (size_t)n * FDIM + 2 * lane);
    const float2 q = __half22float2(qh);

    float acc0 = 0.f, acc1 = 0.f, lsum = 0.f;

    int t = 0;
    int cA = n;                               // self-loop first
    int cB = (d >= 1) ? csr[off] : 0;

    while (t + 1 <= d) {                      // items t and t+1 of d+1 total
        uint2 kv0 = KV[(((unsigned)cA) << 6) + lane];
        uint2 kv1 = KV[(((unsigned)cB) << 6) + lane];
        int cC = (t + 2 <= d) ? csr[off + t + 1] : 0;
        int cD = (t + 3 <= d) ? csr[off + t + 2] : 0;

        __half2 kh0, vh0, kh1, vh1;
        *(unsigned*)&kh0 = kv0.x; *(unsigned*)&vh0 = kv0.y;
        *(unsigned*)&kh1 = kv1.x; *(unsigned*)&vh1 = kv1.y;
        float2 k0 = __half22float2(kh0), v0 = __half22float2(vh0);
        float2 k1 = __half22float2(kh1), v1 = __half22float2(vh1);

        float p0 = q.x * k0.x + q.y * k0.y;
        float p1 = q.x * k1.x + q.y * k1.y;
        p0 += __shfl_xor(p0, 1); p1 += __shfl_xor(p1, 1);
        p0 += __shfl_xor(p0, 2); p1 += __shfl_xor(p1, 2);
        p0 += __shfl_xor(p0, 4); p1 += __shfl_xor(p1, 4);
        float s0 = __expf(p0), s1 = __expf(p1);
        lsum += s0 + s1;
        acc0 += s0 * v0.x + s1 * v1.x;
        acc1 += s0 * v0.y + s1 * v1.y;

        cA = cC; cB = cD; t += 2;
    }
    if (t <= d) {                             // one leftover
        uint2 kv0 = KV[(((unsigned)cA) << 6) + lane];
        __half2 kh0, vh0;
        *(unsigned*)&kh0 = kv0.x; *(unsigned*)&vh0 = kv0.y;
        float2 k0 = __half22float2(kh0), v0 = __half22float2(vh0);
        float p0 = q.x * k0.x + q.y * k0.y;
        p0 += __shfl_xor(p0, 1);
        p0 += __shfl_xor(p0, 2);
        p0 += __shfl_xor(p0, 4);
        float s0 = __expf(p0);
        lsum += s0;
        acc0 += s0 * v0.x;
        acc1 += s0 * v0.y;
    }

    const float inv = 1.0f / lsum;
    float2 o;
    o.x = acc0 * inv;
    o.y = acc1 * inv;
    *(float2*)(out + (size_t)n * FDIM + 2 * lane) = o;
}

// ---------------------------------------------------------------------------
extern "C" void kernel_launch(void* const* d_in, const int* in_sizes, int n_in,
                              void* d_out, int out_size, void* d_ws, size_t ws_size,
                              hipStream_t stream)
{
    const float* x    = (const float*)d_in[0];
    const int*   ei   = (const int*)d_in[1];
    const float* Wq   = (const float*)d_in[2];
    const float* bq   = (const float*)d_in[3];
    const float* Wk   = (const float*)d_in[4];
    const float* bk   = (const float*)d_in[5];
    const float* Wv   = (const float*)d_in[6];
    const float* bias = (const float*)d_in[7];   // final bias, folded into V
    float* out = (float*)d_out;

    const int N = in_sizes[0] / FDIM;
    const int E = in_sizes[1] / 2;
    const int nblk = (N + NROWTILE - 1) / NROWTILE;
    const int Npad = nblk * NROWTILE;

    // workspace layout (~56 MB)
    __half* XH  = (__half*)d_ws;
    __half* WTH = XH + (size_t)Npad * XSTR;
    __half* Qb  = WTH + (size_t)3 * FDIM * XSTR;
    uint2*  KV  = (uint2*)(Qb + (size_t)N * FDIM);        // N x 64 x 8B
    int* deg    = (int*)(KV + (size_t)N * 64);
    int* offs   = deg + N;
    int* cursor = offs + N;
    int* bsum   = cursor + N;
    int* csr    = bsum + 1024;

    hipMemsetAsync(deg, 0, (size_t)N * sizeof(int), stream);

    convert_x_k<<<(Npad * 32 + 255) / 256, 256, 0, stream>>>(x, XH, N, Npad);
    convert_w_k<<<3, 256, 0, stream>>>(Wq, Wk, Wv, WTH);

    gemm_mfma_k<<<nblk, 256, 0, stream>>>(XH, WTH, bq, bk, bias, Qb, KV, N);

    hist_k<<<(E + 255) / 256, 256, 0, stream>>>(ei, E, deg);
    const int nb = (N + 255) / 256;
    scan_block_k<<<nb, 256, 0, stream>>>(deg, offs, bsum, N);
    scan_tops_k<<<1, 256, 0, stream>>>(bsum, nb);
    scan_add_k<<<nb, 256, 0, stream>>>(offs, cursor, bsum, N);
    scatter_k<<<(E + 255) / 256, 256, 0, stream>>>(ei, E, cursor, csr);

    aggregate_k<<<(N + 3) / 4, 256, 0, stream>>>(Qb, KV, offs, deg, csr, out, N);
}

// Round 6
// 273.605 us; speedup vs baseline: 3.0884x; 1.0634x over previous
//
#include <hip/hip_runtime.h>
#include <hip/hip_fp16.h>
#include <cstdint>

#define FDIM 128
#define XSTR 136   // padded row stride in f16 elems (+8 elems = 16 B)
#define NROWTILE 128
#define WCHUNKS ((FDIM * XSTR * 2) / 1024)       // 34 x 1KB chunks per W image
#define XCHUNKS ((NROWTILE * XSTR * 2) / 1024)   // 34 x 1KB chunks per x tile

typedef __attribute__((ext_vector_type(8))) _Float16 half8;
typedef __attribute__((ext_vector_type(2))) _Float16 h2;
typedef __attribute__((ext_vector_type(16))) float float16;

#if defined(__has_builtin)
#if __has_builtin(__builtin_amdgcn_fdot2)
#define HAVE_FDOT2 1
#endif
#endif

__device__ __forceinline__ void gload_lds16(const void* g, void* s) {
    __builtin_amdgcn_global_load_lds(
        (const __attribute__((address_space(1))) void*)g,
        (__attribute__((address_space(3))) void*)s, 16, 0, 0);
}

__device__ __forceinline__ h2 as_h2(unsigned u) {
    union { unsigned u; h2 h; } c; c.u = u; return c.h;
}
__device__ __forceinline__ float2 h2_to_f2(unsigned u) {
    __half2 h = *(__half2*)&u;
    return __half22float2(h);
}

// ---------------------------------------------------------------------------
// Fused prep: convert x -> padded f16 image, convert+transpose 3 W mats,
// and in-degree histogram (threads < E). Grid covers Npad*32 >= E threads.
// ---------------------------------------------------------------------------
__global__ __launch_bounds__(256) void prep_k(
    const float* __restrict__ x, __half* __restrict__ XH,
    const float* __restrict__ Wq, const float* __restrict__ Wk,
    const float* __restrict__ Wv, __half* __restrict__ WTH,
    const int* __restrict__ ei, int* __restrict__ deg,
    int N, int Npad, int E)
{
    int idx = blockIdx.x * 256 + threadIdx.x;

    if (idx < Npad * 32) {                      // one float4 of x per thread
        int row = idx >> 5;
        int c = (idx & 31) << 2;
        float4 v = make_float4(0.f, 0.f, 0.f, 0.f);
        if (row < N) v = *(const float4*)(x + (size_t)row * FDIM + c);
        __half h[4] = {__float2half_rn(v.x), __float2half_rn(v.y),
                       __float2half_rn(v.z), __float2half_rn(v.w)};
        *(ushort4*)(XH + (size_t)row * XSTR + c) = *(ushort4*)h;
    }

    if (idx < 3 * FDIM * FDIM) {                // W convert+transpose
        int mat = idx >> 14;                    // 16384 elems per mat
        int m = idx & 16383;
        int k = m >> 7;
        int nn = m & 127;
        const float* __restrict__ W = (mat == 0) ? Wq : (mat == 1) ? Wk : Wv;
        WTH[(size_t)mat * FDIM * XSTR + nn * XSTR + k] =
            __float2half_rn(W[k * FDIM + nn]);
    }

    if (idx < E) atomicAdd(&deg[ei[idx]], 1);   // in-degree histogram
}

// ---------------------------------------------------------------------------
// MFMA GEMM (f16): per block 128 rows x 128 cols, loops all 3 mats.
// Outputs: Q -> f16 Qb[N][128]; K,V -> interleaved KV uint2[N][64]
// (dim pair 2j,2j+1: .x = K halves, .y = V halves) for single-load gathers.
// relu on Q,K; final bias folded into V (sum alpha = 1).
// LDS = 2 * 128*136*2 = 69.6 KB -> 2 blocks/CU.
// ---------------------------------------------------------------------------
__global__ __launch_bounds__(256) void gemm_mfma_k(
    const __half* __restrict__ XH, const __half* __restrict__ WTH,
    const float* __restrict__ bq, const float* __restrict__ bk,
    const float* __restrict__ bias,
    __half* __restrict__ Qb, uint2* __restrict__ KV, int N)
{
    __shared__ __half xs[NROWTILE * XSTR];
    __shared__ __half ws[FDIM * XSTR];

    const int tid  = threadIdx.x;
    const int wave = tid >> 6;
    const int lane = tid & 63;
    const int r0   = blockIdx.x * NROWTILE;

    for (int c = wave; c < XCHUNKS; c += 4) {
        gload_lds16((const char*)(XH + (size_t)r0 * XSTR) + c * 1024 + lane * 16,
                    (char*)xs + c * 1024);
        gload_lds16((const char*)WTH + c * 1024 + lane * 16,
                    (char*)ws + c * 1024);
    }
    __syncthreads();

    const int mrow = lane & 31;    // A row within 32-tile / B,C col within 32
    const int half = lane >> 5;    // 0/1
    const int arow = wave * 32 + mrow;

    for (int mat = 0; mat < 3; ++mat) {
        float16 acc[4];
        #pragma unroll
        for (int nt = 0; nt < 4; ++nt)
            #pragma unroll
            for (int r = 0; r < 16; ++r) acc[nt][r] = 0.f;

        #pragma unroll
        for (int ks = 0; ks < 8; ++ks) {
            const int ko = ks * 16 + half * 8;
            half8 ah = *(const half8*)(xs + arow * XSTR + ko);
            #pragma unroll
            for (int nt = 0; nt < 4; ++nt) {
                half8 bh = *(const half8*)(ws + (nt * 32 + mrow) * XSTR + ko);
                acc[nt] = __builtin_amdgcn_mfma_f32_32x32x16_f16(ah, bh, acc[nt], 0, 0, 0);
            }
        }

        __syncthreads();
        if (mat < 2) {   // prefetch next mat's FULL W image (34 chunks)
            const char* nh = (const char*)(WTH + (size_t)(mat + 1) * FDIM * XSTR);
            for (int c = wave; c < WCHUNKS; c += 4)
                gload_lds16(nh + c * 1024 + lane * 16, (char*)ws + c * 1024);
        }

        // epilogue: C/D layout col=lane&31, row=(reg&3)+8*(reg>>2)+4*(lane>>5)
        const float* bvec = (mat == 0) ? bq : (mat == 1) ? bk : bias;
        __half* kvh = (__half*)KV;
        #pragma unroll
        for (int nt = 0; nt < 4; ++nt) {
            const int col = nt * 32 + mrow;
            const float bb = bvec[col];
            #pragma unroll
            for (int reg = 0; reg < 16; ++reg) {
                int rl = (reg & 3) + 8 * (reg >> 2) + 4 * half;
                int row = r0 + wave * 32 + rl;
                if (row < N) {
                    float v = acc[nt][reg] + bb;
                    if (mat < 2) v = fmaxf(v, 0.f);
                    __half hv = __float2half_rn(v);
                    if (mat == 0) {
                        Qb[(size_t)row * FDIM + col] = hv;
                    } else {
                        // K at slot 0/1, V at slot 2/3 of the dim-pair group
                        kvh[(size_t)row * 256 + (col >> 1) * 4 + (col & 1) +
                            ((mat == 2) ? 2 : 0)] = hv;
                    }
                }
            }
        }
        __syncthreads();
    }
}

// ---------------------------------------------------------------------------
// CSR build: block-local scan, then fused top-scan + fixup, then scatter.
// ---------------------------------------------------------------------------
__global__ __launch_bounds__(256) void scan_block_k(const int* __restrict__ deg,
                                                    int* __restrict__ offs,
                                                    int* __restrict__ bsum, int N)
{
    __shared__ int sh[256];
    int g = blockIdx.x * 256 + threadIdx.x;
    int v = (g < N) ? deg[g] : 0;
    sh[threadIdx.x] = v;
    __syncthreads();
    for (int s = 1; s < 256; s <<= 1) {
        int t = (threadIdx.x >= s) ? sh[threadIdx.x - s] : 0;
        __syncthreads();
        sh[threadIdx.x] += t;
        __syncthreads();
    }
    if (g < N) offs[g] = sh[threadIdx.x] - v;
    if (threadIdx.x == 255) bsum[blockIdx.x] = sh[255];
}

// Each block redundantly scans the <=256 block sums in LDS, takes its own
// exclusive prefix, and applies it (replaces scan_tops + scan_add).
__global__ __launch_bounds__(256) void scan_add_k(int* __restrict__ offs,
                                                  int* __restrict__ cursor,
                                                  const int* __restrict__ bsum,
                                                  int N, int nb)
{
    __shared__ int sh[256];
    int v = (threadIdx.x < nb) ? bsum[threadIdx.x] : 0;
    sh[threadIdx.x] = v;
    __syncthreads();
    for (int s = 1; s < 256; s <<= 1) {
        int t = (threadIdx.x >= s) ? sh[threadIdx.x - s] : 0;
        __syncthreads();
        sh[threadIdx.x] += t;
        __syncthreads();
    }
    int prefix = (blockIdx.x == 0) ? 0 : sh[blockIdx.x - 1];
    int g = blockIdx.x * 256 + threadIdx.x;
    if (g < N) {
        int o = offs[g] + prefix;
        offs[g] = o;
        cursor[g] = o;
    }
}

__global__ __launch_bounds__(256) void scatter_k(const int* __restrict__ ei, int E,
                                                 int* __restrict__ cursor,
                                                 int* __restrict__ csr)
{
    int e = blockIdx.x * 256 + threadIdx.x;
    if (e < E) {
        int row = ei[e];
        int col = ei[E + e];
        int slot = atomicAdd(&cursor[row], 1);
        csr[slot] = col;
    }
}

// ---------------------------------------------------------------------------
// Aggregation: one wave per node; lane l owns dims 2l,2l+1 (head = l/8).
// Single uint2 gather per item (K+V interleaved), unroll-4 index pipeline
// (4 gathers in flight), fdot2 for the score. Scores >= 0 and bounded ->
// single-pass softmax, no max subtraction.
// ---------------------------------------------------------------------------
__global__ __launch_bounds__(256) void aggregate_k(
    const __half* __restrict__ Qb, const uint2* __restrict__ KV,
    const int* __restrict__ offs, const int* __restrict__ deg,
    const int* __restrict__ csr,
    float* __restrict__ out, int N)
{
    const int lane = threadIdx.x & 63;
    int n = blockIdx.x * 4 + (threadIdx.x >> 6);
    if (n >= N) return;
    n = __builtin_amdgcn_readfirstlane(n);

    const int d     = __builtin_amdgcn_readfirstlane(deg[n]);
    const int off   = __builtin_amdgcn_readfirstlane(offs[n]);
    const int total = d + 1;                  // + self loop

    const unsigned qu = *(const unsigned*)(Qb + (size_t)n * FDIM + 2 * lane);
    const h2 q2 = as_h2(qu);
    const float2 qf = h2_to_f2(qu);
    (void)qf;

    float acc0 = 0.f, acc1 = 0.f, lsum = 0.f;

    auto proc = [&](uint2 kv) {
#ifdef HAVE_FDOT2
        float p = __builtin_amdgcn_fdot2(as_h2(kv.x), q2, 0.0f, false);
#else
        float2 kf = h2_to_f2(kv.x);
        float p = qf.x * kf.x + qf.y * kf.y;
#endif
        p += __shfl_xor(p, 1);
        p += __shfl_xor(p, 2);
        p += __shfl_xor(p, 4);               // 8-lane head group reduced
        float s = __expf(p);
        float2 vf = h2_to_f2(kv.y);
        lsum += s;
        acc0 += s * vf.x;
        acc1 += s * vf.y;
    };

    // item j: j==0 -> self (n), j>=1 -> csr[off + j - 1]
    int t = 0;
    int c0 = n;
    int c1 = (1 < total) ? csr[off + 0] : 0;
    int c2 = (2 < total) ? csr[off + 1] : 0;
    int c3 = (3 < total) ? csr[off + 2] : 0;

    while (t + 4 <= total) {
        uint2 kv0 = KV[(((unsigned)c0) << 6) + lane];
        uint2 kv1 = KV[(((unsigned)c1) << 6) + lane];
        uint2 kv2 = KV[(((unsigned)c2) << 6) + lane];
        uint2 kv3 = KV[(((unsigned)c3) << 6) + lane];
        int n0 = (t + 4 < total) ? csr[off + t + 3] : 0;
        int n1 = (t + 5 < total) ? csr[off + t + 4] : 0;
        int n2 = (t + 6 < total) ? csr[off + t + 5] : 0;
        int n3 = (t + 7 < total) ? csr[off + t + 6] : 0;
        proc(kv0); proc(kv1); proc(kv2); proc(kv3);
        c0 = n0; c1 = n1; c2 = n2; c3 = n3;
        t += 4;
    }
    if (t     < total) proc(KV[(((unsigned)c0) << 6) + lane]);
    if (t + 1 < total) proc(KV[(((unsigned)c1) << 6) + lane]);
    if (t + 2 < total) proc(KV[(((unsigned)c2) << 6) + lane]);

    const float inv = 1.0f / lsum;
    float2 o;
    o.x = acc0 * inv;
    o.y = acc1 * inv;
    *(float2*)(out + (size_t)n * FDIM + 2 * lane) = o;
}

// ---------------------------------------------------------------------------
extern "C" void kernel_launch(void* const* d_in, const int* in_sizes, int n_in,
                              void* d_out, int out_size, void* d_ws, size_t ws_size,
                              hipStream_t stream)
{
    const float* x    = (const float*)d_in[0];
    const int*   ei   = (const int*)d_in[1];
    const float* Wq   = (const float*)d_in[2];
    const float* bq   = (const float*)d_in[3];
    const float* Wk   = (const float*)d_in[4];
    const float* bk   = (const float*)d_in[5];
    const float* Wv   = (const float*)d_in[6];
    const float* bias = (const float*)d_in[7];   // final bias, folded into V
    float* out = (float*)d_out;

    const int N = in_sizes[0] / FDIM;
    const int E = in_sizes[1] / 2;
    const int nblk = (N + NROWTILE - 1) / NROWTILE;
    const int Npad = nblk * NROWTILE;

    // workspace layout (~56 MB)
    __half* XH  = (__half*)d_ws;
    __half* WTH = XH + (size_t)Npad * XSTR;
    __half* Qb  = WTH + (size_t)3 * FDIM * XSTR;
    uint2*  KV  = (uint2*)(Qb + (size_t)N * FDIM);        // N x 64 x 8B
    int* deg    = (int*)(KV + (size_t)N * 64);
    int* offs   = deg + N;
    int* cursor = offs + N;
    int* bsum   = cursor + N;
    int* csr    = bsum + 1024;

    hipMemsetAsync(deg, 0, (size_t)N * sizeof(int), stream);

    prep_k<<<(Npad * 32 + 255) / 256, 256, 0, stream>>>(
        x, XH, Wq, Wk, Wv, WTH, ei, deg, N, Npad, E);

    gemm_mfma_k<<<nblk, 256, 0, stream>>>(XH, WTH, bq, bk, bias, Qb, KV, N);

    const int nb = (N + 255) / 256;   // 196 <= 256
    scan_block_k<<<nb, 256, 0, stream>>>(deg, offs, bsum, N);
    scan_add_k<<<nb, 256, 0, stream>>>(offs, cursor, bsum, N, nb);
    scatter_k<<<(E + 255) / 256, 256, 0, stream>>>(ei, E, cursor, csr);

    aggregate_k<<<(N + 3) / 4, 256, 0, stream>>>(Qb, KV, offs, deg, csr, out, N);
}